// Round 10
// baseline (158.698 us; speedup 1.0000x reference)
//
#include <hip/hip_runtime.h>
#include <hip/hip_bf16.h>
#include <math.h>

// N=50000, E=800000, IN_DIM=128, HEADS=8, F_OUT=16, HF=128.
#define PADN 50048
#define CAP 64       // slots per node bucket; deg ~ Poisson(16), P(>64)~1e-21
#define NBIN 98      // node bins of 512: covers [0, 50176)
#define BINSZ 512
#define SEGCAP 9216  // per-bin segment capacity; mean 8163, +11 sigma
#define EPB 4096     // edges per partition block (R10: halved -> 196 blocks)
#define INVALID 0xFFFFFFFFu

typedef __attribute__((ext_vector_type(8))) short short8;
typedef __attribute__((ext_vector_type(4))) float f32x4;
typedef __attribute__((ext_vector_type(4))) unsigned int uint4v;

__device__ __forceinline__ unsigned short f2b(float f) {
  __hip_bfloat16 h = __float2bfloat16(f);
  return *(unsigned short*)&h;
}

// ---------------------------------------------------------------------------
// Shared GEMM block body (M=32/wave, 128 rows/block, ping-pong B from
// L2-resident Bpk). Called from BOTH k_pg and k_csr so each serial binning
// stage has co-resident MFMA work to hide its latency (R10 split).
// ---------------------------------------------------------------------------
__device__ void gemm_block(const float* __restrict__ x,
                           const unsigned short* __restrict__ Bpk,
                           unsigned short* __restrict__ pb,
                           unsigned short* __restrict__ sb,
                           float* __restrict__ ssrc, float* __restrict__ stgt,
                           int N, int rowBase, int tid) {
  const int wave = tid >> 6, lane = tid & 63;
  const int m = lane & 15, q = lane >> 4;
  const int r0 = rowBase + wave * 32;

  short8 a[2][4];
#pragma unroll
  for (int g = 0; g < 2; ++g) {
    const int row_a = r0 + g * 16 + m;
#pragma unroll
    for (int ks = 0; ks < 4; ++ks) {
      float4 v0 = make_float4(0.f, 0.f, 0.f, 0.f), v1 = v0;
      if (row_a < N) {
        const float4* xp = (const float4*)(x + (size_t)row_a * 128 + ks * 32 + q * 8);
        v0 = xp[0];
        v1 = xp[1];
      }
      unsigned short o[8];
      o[0] = f2b(v0.x); o[1] = f2b(v0.y); o[2] = f2b(v0.z); o[3] = f2b(v0.w);
      o[4] = f2b(v1.x); o[5] = f2b(v1.y); o[6] = f2b(v1.z); o[7] = f2b(v1.w);
      a[g][ks] = *(short8*)o;
    }
  }

#define LOADB(dst, t)                                                        \
  {                                                                          \
    const unsigned short* bp_ = Bpk + (size_t)((t) * 256 + lane) * 8;        \
    dst[0] = *(const short8*)(bp_ + 0 * 512);                                \
    dst[1] = *(const short8*)(bp_ + 1 * 512);                                \
    dst[2] = *(const short8*)(bp_ + 2 * 512);                                \
    dst[3] = *(const short8*)(bp_ + 3 * 512);                                \
  }

  short8 bb[2][4];
  LOADB(bb[0], 0)
#pragma unroll
  for (int ct = 0; ct < 17; ++ct) {
    if (ct < 16) LOADB(bb[(ct + 1) & 1], ct + 1)
    f32x4 acc0 = {0.f, 0.f, 0.f, 0.f};
    f32x4 acc1 = {0.f, 0.f, 0.f, 0.f};
#pragma unroll
    for (int ks = 0; ks < 4; ++ks) {
      acc0 = __builtin_amdgcn_mfma_f32_16x16x32_bf16(a[0][ks], bb[ct & 1][ks], acc0, 0, 0, 0);
      acc1 = __builtin_amdgcn_mfma_f32_16x16x32_bf16(a[1][ks], bb[ct & 1][ks], acc1, 0, 0, 0);
    }
    if (ct < 16) {
      unsigned short* dst = (ct < 8) ? pb : sb;
      const int cc = (ct & 7) * 16 + m;
#pragma unroll
      for (int r = 0; r < 4; ++r) {
        int row0 = r0 + q * 4 + r;
        if (row0 < N) dst[(size_t)row0 * 128 + cc] = f2b(acc0[r]);
        int row1 = r0 + 16 + q * 4 + r;
        if (row1 < N) dst[(size_t)row1 * 128 + cc] = f2b(acc1[r]);
      }
    } else {  // score tile: cols 0-7 = s_src heads, 8-15 = s_tgt heads
      float* sd = (m < 8) ? ssrc : stgt;
      const int h = m & 7;
#pragma unroll
      for (int r = 0; r < 4; ++r) {
        int row0 = r0 + q * 4 + r;
        if (row0 < N) sd[row0 * 8 + h] = acc0[r];
        int row1 = r0 + 16 + q * 4 + r;
        if (row1 < N) sd[row1 * 8 + h] = acc1[r];
      }
    }
  }
#undef LOADB
}

// ---------------------------------------------------------------------------
// K_init: blocks 0-16 W-pack into MFMA B-frag order (17 tiles: 0-7 W_proj,
// 8-15 W_skip, 16 folded score matrix); block 17 inits the 98 bin cursors.
// ---------------------------------------------------------------------------
__global__ __launch_bounds__(256) void k_init(const float* __restrict__ Wp,
                                              const float* __restrict__ Ws,
                                              const float* __restrict__ a_src,
                                              const float* __restrict__ a_tgt,
                                              unsigned short* __restrict__ Bpk,
                                              int* __restrict__ cursor) {
  const int b = blockIdx.x;
  if (b == 17) {
    if (threadIdx.x < NBIN) cursor[threadIdx.x] = threadIdx.x * SEGCAP;
    return;
  }
  // W-pack: Bpk[((tile*4+ks)*64+lane)*8 + j], k = ks*32+(lane>>4)*8+j
  int idx = b * 256 + threadIdx.x;  // 0..4351
  int tile = idx >> 8;
  int ks = (idx >> 6) & 3;
  int lane = idx & 63;
  int kbase = ks * 32 + (lane >> 4) * 8;
  unsigned short o[8];
  if (tile < 16) {
    int col = tile * 16 + (lane & 15);
    const float* src = (col < 128) ? (Wp + (size_t)col * 128 + kbase)
                                   : (Ws + (size_t)(col - 128) * 128 + kbase);
#pragma unroll
    for (int j = 0; j < 8; ++j) o[j] = f2b(src[j]);
  } else {  // folded score tile
    int col = lane & 15;
    int h = col & 7;
    const float* av = (col < 8) ? (a_src + h * 16) : (a_tgt + h * 16);
#pragma unroll
    for (int j = 0; j < 8; ++j) {
      int k = kbase + j;
      float s = 0.f;
#pragma unroll
      for (int f = 0; f < 16; ++f) s = fmaf(Wp[(size_t)(h * 16 + f) * 128 + k], av[f], s);
      o[j] = f2b(s);
    }
  }
  *(short8*)(Bpk + (size_t)idx * 8) = *(short8*)o;
}

// ---------------------------------------------------------------------------
// K_pg, R10: partition blocks (EPB 4096 -> 196 blocks, half the per-block
// serial chain of R9) + first half of the GEMM (rows [0, gemmB1*128)).
// Per-wave sub-histograms/scatter counters (R9 de-contention), ord[] stays
// bin-contiguous for the coalesced flush, one cursor atomic per (block,bin).
// ---------------------------------------------------------------------------
__global__ __launch_bounds__(256) void k_pg(
    const float* __restrict__ x, const unsigned short* __restrict__ Bpk,
    unsigned short* __restrict__ pb, unsigned short* __restrict__ sb,
    float* __restrict__ ssrc, float* __restrict__ stgt,
    const int* __restrict__ ei, int* __restrict__ cursor,
    unsigned int* __restrict__ binned, int N, int E, int partB) {
  __shared__ unsigned int ord[EPB];        // 16 KB
  __shared__ int hist_w[4][128];           // per-wave histograms
  __shared__ int woff_[4][128];            // intra-bin wave offsets
  __shared__ int posw_[4][128];            // per-wave running counters
  __shared__ int base_[128], scn[128], mybase[128];
  const int b = blockIdx.x;
  if (b < partB) {
    const int tid = threadIdx.x;
    const int wv = tid >> 6;
    const int e0 = b * EPB;
    const int ne = min(EPB, E - e0);
    const int* srcp = ei;
    const int* tgtp = ei + E;
    for (int i = tid; i < 512; i += 256) {
      ((int*)hist_w)[i] = 0;
      ((int*)posw_)[i] = 0;
    }
    __syncthreads();
    unsigned int pk[16];
#pragma unroll
    for (int j = 0; j < 4; ++j) {
      int e4 = e0 + (j * 256 + tid) * 4;
      if (e4 < E) {  // E%4==0, e4%4==0 -> full uint4 in bounds
        uint4v t4 = *(const uint4v*)(tgtp + e4);
        uint4v s4 = *(const uint4v*)(srcp + e4);
#pragma unroll
        for (int k = 0; k < 4; ++k) {
          pk[j * 4 + k] = (t4[k] << 16) | s4[k];
          atomicAdd(&hist_w[wv][t4[k] >> 9], 1);
        }
      } else {
#pragma unroll
        for (int k = 0; k < 4; ++k) pk[j * 4 + k] = INVALID;
      }
    }
    __syncthreads();
    if (tid < 128) {
      int w0 = hist_w[0][tid], w1 = hist_w[1][tid];
      int w2 = hist_w[2][tid], w3 = hist_w[3][tid];
      woff_[0][tid] = 0;
      woff_[1][tid] = w0;
      woff_[2][tid] = w0 + w1;
      woff_[3][tid] = w0 + w1 + w2;
      scn[tid] = w0 + w1 + w2 + w3;
    }
    __syncthreads();
    int c = (tid < 128) ? scn[tid] : 0;
#pragma unroll
    for (int off = 1; off < 128; off <<= 1) {
      int v = 0;
      if (tid < 128 && tid >= off) v = scn[tid - off];
      __syncthreads();
      if (tid < 128) scn[tid] += v;
      __syncthreads();
    }
    if (tid < 128) {
      base_[tid] = scn[tid] - c;  // exclusive base
      mybase[tid] = (tid < NBIN && c > 0) ? atomicAdd(&cursor[tid], c) : 0;
    }
    __syncthreads();
#pragma unroll
    for (int j = 0; j < 16; ++j) {
      if (pk[j] != INVALID) {
        int bb = pk[j] >> 25;  // = tgt>>9
        int r = atomicAdd(&posw_[wv][bb], 1);
        ord[base_[bb] + woff_[wv][bb] + r] = pk[j];
      }
    }
    __syncthreads();
    for (int i = tid; i < ne; i += 256) {
      unsigned int p = ord[i];
      int bb = p >> 25;
      int gpos = mybase[bb] + (i - base_[bb]);
      if (gpos < (bb + 1) * SEGCAP) binned[gpos] = p;  // coalesced bin-runs
    }
    return;
  }
  gemm_block(x, Bpk, pb, sb, ssrc, stgt, N, (b - partB) * 128, threadIdx.x);
}

// ---------------------------------------------------------------------------
// K_csr, R10: 392 quarter-bin CSR blocks (R9) + the SECOND half of the GEMM
// (rows [gemmB1*128, PADN)) as co-resident latency filler — R9 ran this
// stage naked. Block (g,q) scans bin g's segment (uint4 streaming) and ranks
// its 128-node slice into a 16 KB LDS bucket, then flushes coalesced.
// ---------------------------------------------------------------------------
__global__ __launch_bounds__(256) void k_csr(const unsigned int* __restrict__ binned,
                                             const int* __restrict__ cursor,
                                             int* __restrict__ counts,
                                             unsigned short* __restrict__ esrc,
                                             const float* __restrict__ x,
                                             const unsigned short* __restrict__ Bpk,
                                             unsigned short* __restrict__ pb,
                                             unsigned short* __restrict__ sb,
                                             float* __restrict__ ssrc,
                                             float* __restrict__ stgt,
                                             int N, int csrB, int rowBase) {
  __shared__ unsigned short buck[128 * CAP];  // 16 KB
  __shared__ int cnt128[128];
  const int blk = blockIdx.x;
  if (blk >= csrB) {
    gemm_block(x, Bpk, pb, sb, ssrc, stgt, N, rowBase + (blk - csrB) * 128,
               threadIdx.x);
    return;
  }
  const int g = blk >> 2, qq = blk & 3, tid = threadIdx.x;
  const int lo = g * BINSZ + qq * 128;
  for (int i = tid; i < 128; i += 256) cnt128[i] = 0;
  __syncthreads();
  const int cnt = min(cursor[g] - g * SEGCAP, SEGCAP);
  const unsigned int* seg = binned + (size_t)g * SEGCAP;
  const int c4 = cnt >> 2;
  for (int i = tid; i < c4; i += 256) {
    uint4v p4 = *(const uint4v*)(seg + i * 4);
#pragma unroll
    for (int k = 0; k < 4; ++k) {
      unsigned int p = p4[k];
      int tl = (p >> 16) & (BINSZ - 1);
      if ((tl >> 7) == qq) {
        int r = atomicAdd(&cnt128[tl & 127], 1);
        if (r < CAP) buck[((tl & 127) << 6) + r] = (unsigned short)(p & 0xFFFFu);
      }
    }
  }
  for (int i = c4 * 4 + tid; i < cnt; i += 256) {
    unsigned int p = seg[i];
    int tl = (p >> 16) & (BINSZ - 1);
    if ((tl >> 7) == qq) {
      int r = atomicAdd(&cnt128[tl & 127], 1);
      if (r < CAP) buck[((tl & 127) << 6) + r] = (unsigned short)(p & 0xFFFFu);
    }
  }
  __syncthreads();
  uint4* dst = (uint4*)(esrc + ((size_t)lo << 6));
  const uint4* s4 = (const uint4*)buck;
  for (int v = tid; v < (128 * CAP) / 8; v += 256) dst[v] = s4[v];
  for (int i = tid; i < 128; i += 256) {
    int n = lo + i;
    if (n < N) counts[n] = min(cnt128[i], CAP);
  }
}

// ---------------------------------------------------------------------------
// K_agg (R8 VALU-lean version, unchanged): Phase A computes per-slot weights
// for all 8 heads once (lane j owns slot j; 9-padded LDS row); Phase B is
// one broadcast ds_read + one scalar-based pb gather + 2 fma per edge,
// branch-free tail. Fused skip+bias+ELU.
// ---------------------------------------------------------------------------
__global__ __launch_bounds__(256) void k_agg(const unsigned short* __restrict__ pb,
                                             const unsigned short* __restrict__ sb,
                                             const float* __restrict__ ssrc,
                                             const float* __restrict__ stgt,
                                             const float* __restrict__ bias,
                                             const int* __restrict__ counts,
                                             const unsigned short* __restrict__ esrc,
                                             float* __restrict__ out, int N) {
  __shared__ float w_lds[4][64 * 9];
  int wid = (int)((blockIdx.x * (size_t)blockDim.x + threadIdx.x) >> 6);
  int lane = threadIdx.x & 63;
  if (wid >= N) return;
  const int n = wid;
  const int wv = threadIdx.x >> 6;
  const int c = lane * 2;
  const int h = lane >> 3;

  const int cnt = min(counts[n], CAP);
  const int srcv = (int)esrc[(n << 6) + lane];

  {
    const bool val = lane < cnt;
    const int s_safe = val ? srcv : 0;
    const float4* sp = (const float4*)(ssrc + s_safe * 8);
    float4 s01 = sp[0], s23 = sp[1];
    const float4* tp = (const float4*)(stgt + n * 8);
    float4 t01 = tp[0], t23 = tp[1];
    float w[8];
    w[0] = s01.x + t01.x; w[1] = s01.y + t01.y;
    w[2] = s01.z + t01.z; w[3] = s01.w + t01.w;
    w[4] = s23.x + t23.x; w[5] = s23.y + t23.y;
    w[6] = s23.z + t23.z; w[7] = s23.w + t23.w;
#pragma unroll
    for (int k = 0; k < 8; ++k) {
      float e_ = fmaxf(w[k], 0.2f * w[k]);
      w[k] = val ? __expf(e_) : 0.0f;
    }
    float* wr = &w_lds[wv][lane * 9];
#pragma unroll
    for (int k = 0; k < 8; ++k) wr[k] = w[k];
  }

  float ds0 = 0.f, ds1 = 0.f, ds2 = 0.f, ds3 = 0.f;
  float x00 = 0.f, x01 = 0.f, x10 = 0.f, x11 = 0.f;
  float x20 = 0.f, x21 = 0.f, x30 = 0.f, x31 = 0.f;

#define LOADP(p, jj)                                                   \
  {                                                                    \
    int s_ = __builtin_amdgcn_readlane(srcv, min((jj), cm));           \
    pv##p = *(const unsigned int*)(pb + (size_t)s_ * 128 + c);         \
  }
#define CONS(p, dsx, a0x, a1x, jj)                                     \
  {                                                                    \
    float w_ = w_lds[wv][(jj) * 9 + h];                                \
    dsx += w_;                                                         \
    a0x = fmaf(w_, __uint_as_float(pv##p << 16), a0x);                 \
    a1x = fmaf(w_, __uint_as_float(pv##p & 0xffff0000u), a1x);         \
  }

  const int p8 = (cnt + 7) & ~7;
  if (p8 > 0) {
    const int cm = cnt - 1;
    unsigned int pv0, pv1, pv2, pv3, pv4, pv5, pv6, pv7;
    LOADP(0, 0) LOADP(1, 1) LOADP(2, 2) LOADP(3, 3)
    LOADP(4, 4) LOADP(5, 5) LOADP(6, 6) LOADP(7, 7)
    for (int j = 0; j + 8 <= p8; j += 8) {
      CONS(0, ds0, x00, x01, j + 0)
      CONS(1, ds1, x10, x11, j + 1)
      CONS(2, ds2, x20, x21, j + 2)
      CONS(3, ds3, x30, x31, j + 3)
      if (j + 8 < p8) {
        LOADP(0, j + 8) LOADP(1, j + 9) LOADP(2, j + 10) LOADP(3, j + 11)
      }
      CONS(4, ds0, x00, x01, j + 4)
      CONS(5, ds1, x10, x11, j + 5)
      CONS(6, ds2, x20, x21, j + 6)
      CONS(7, ds3, x30, x31, j + 7)
      if (j + 8 < p8) {
        LOADP(4, j + 12) LOADP(5, j + 13) LOADP(6, j + 14) LOADP(7, j + 15)
      }
    }
  }
#undef LOADP
#undef CONS

  const float dsum = (ds0 + ds1) + (ds2 + ds3);
  const float acc0 = (x00 + x10) + (x20 + x30);
  const float acc1 = (x01 + x11) + (x21 + x31);
  const float inv = 1.0f / (dsum + 1e-16f);
  size_t row = (size_t)n * 128;
  unsigned int su = *(const unsigned int*)(sb + row + c);
  float sk0 = __uint_as_float(su << 16);
  float sk1 = __uint_as_float(su & 0xffff0000u);
  float r0 = fmaf(acc0, inv, sk0) + bias[c];
  float r1 = fmaf(acc1, inv, sk1) + bias[c + 1];
  r0 = (r0 > 0.f) ? r0 : (__expf(r0) - 1.0f);  // ELU
  r1 = (r1 > 0.f) ? r1 : (__expf(r1) - 1.0f);
  *(float2*)(out + row + c) = make_float2(r0, r1);
}

// ---------------------------------------------------------------------------
extern "C" void kernel_launch(void* const* d_in, const int* in_sizes, int n_in,
                              void* d_out, int out_size, void* d_ws, size_t ws_size,
                              hipStream_t stream) {
  const float* x = (const float*)d_in[0];
  const int* ei = (const int*)d_in[1];
  const float* Wp = (const float*)d_in[2];
  const float* a_src = (const float*)d_in[3];
  const float* a_tgt = (const float*)d_in[4];
  const float* Ws = (const float*)d_in[5];
  const float* bias = (const float*)d_in[6];
  float* out = (float*)d_out;

  const int N = in_sizes[0] / 128;  // 50000
  const int E = in_sizes[1] / 2;    // 800000

  // workspace layout (~39.1 MB), all 16B-aligned
  unsigned short* Bpk = (unsigned short*)d_ws;            // 34816 bf16
  unsigned short* pb = Bpk + 34816;                       // N*128 bf16
  unsigned short* sb = pb + (size_t)N * 128;              // N*128 bf16
  float* ssrc = (float*)(sb + (size_t)N * 128);           // N*8
  float* stgt = ssrc + (size_t)N * 8;                     // N*8
  int* counts = (int*)(stgt + (size_t)N * 8);             // N
  unsigned short* esrcU = (unsigned short*)(counts + N);  // NBIN*512*64 ushort
  unsigned int* binned = (unsigned int*)(esrcU + (size_t)NBIN * BINSZ * CAP);
  int* cursor = (int*)(binned + (size_t)NBIN * SEGCAP);   // NBIN

  const int partB = (E + EPB - 1) / EPB;  // 196 partition blocks
  const int gemmB = PADN / 128;           // 391 gemm blocks total
  const int gemmB1 = 196;                 // co-resident with partition
  const int gemmB2 = gemmB - gemmB1;      // 195, co-resident with CSR
  const int csrB = NBIN * 4;              // 392 quarter-bin CSR blocks

  k_init<<<18, 256, 0, stream>>>(Wp, Ws, a_src, a_tgt, Bpk, cursor);
  k_pg<<<partB + gemmB1, 256, 0, stream>>>(x, Bpk, pb, sb, ssrc, stgt, ei, cursor,
                                           binned, N, E, partB);
  k_csr<<<csrB + gemmB2, 256, 0, stream>>>(binned, cursor, counts, esrcU,
                                           x, Bpk, pb, sb, ssrc, stgt,
                                           N, csrB, gemmB1 * 128);
  k_agg<<<(N + 3) / 4, 256, 0, stream>>>(pb, sb, ssrc, stgt, bias, counts, esrcU, out, N);
}

// Round 11
// 153.477 us; speedup vs baseline: 1.0340x; 1.0340x over previous
//
#include <hip/hip_runtime.h>
#include <hip/hip_bf16.h>
#include <math.h>

// N=50000, E=800000, IN_DIM=128, HEADS=8, F_OUT=16, HF=128.
#define PADN 50048
#define CAP 64       // slots per node bucket; deg ~ Poisson(16), P(>64)~1e-21
#define NBIN 98      // node bins of 512: covers [0, 50176)
#define BINSZ 512
#define SEGCAP 9216  // per-bin segment capacity; mean 8163, +11 sigma
#define EPB 8192     // edges per partition block (R11: reverted to R9 value)
#define INVALID 0xFFFFFFFFu

typedef __attribute__((ext_vector_type(8))) short short8;
typedef __attribute__((ext_vector_type(4))) float f32x4;
typedef __attribute__((ext_vector_type(4))) unsigned int uint4v;

__device__ __forceinline__ unsigned short f2b(float f) {
  __hip_bfloat16 h = __float2bfloat16(f);
  return *(unsigned short*)&h;
}

// ---------------------------------------------------------------------------
// K_init: blocks 0-16 W-pack into MFMA B-frag order (17 tiles: 0-7 W_proj,
// 8-15 W_skip, 16 folded score matrix); block 17 inits the 98 bin cursors.
// ---------------------------------------------------------------------------
__global__ __launch_bounds__(256) void k_init(const float* __restrict__ Wp,
                                              const float* __restrict__ Ws,
                                              const float* __restrict__ a_src,
                                              const float* __restrict__ a_tgt,
                                              unsigned short* __restrict__ Bpk,
                                              int* __restrict__ cursor) {
  const int b = blockIdx.x;
  if (b == 17) {
    if (threadIdx.x < NBIN) cursor[threadIdx.x] = threadIdx.x * SEGCAP;
    return;
  }
  // W-pack: Bpk[((tile*4+ks)*64+lane)*8 + j], k = ks*32+(lane>>4)*8+j
  int idx = b * 256 + threadIdx.x;  // 0..4351
  int tile = idx >> 8;
  int ks = (idx >> 6) & 3;
  int lane = idx & 63;
  int kbase = ks * 32 + (lane >> 4) * 8;
  unsigned short o[8];
  if (tile < 16) {
    int col = tile * 16 + (lane & 15);
    const float* src = (col < 128) ? (Wp + (size_t)col * 128 + kbase)
                                   : (Ws + (size_t)(col - 128) * 128 + kbase);
#pragma unroll
    for (int j = 0; j < 8; ++j) o[j] = f2b(src[j]);
  } else {  // folded score tile
    int col = lane & 15;
    int h = col & 7;
    const float* av = (col < 8) ? (a_src + h * 16) : (a_tgt + h * 16);
#pragma unroll
    for (int j = 0; j < 8; ++j) {
      int k = kbase + j;
      float s = 0.f;
#pragma unroll
      for (int f = 0; f < 16; ++f) s = fmaf(Wp[(size_t)(h * 16 + f) * 128 + k], av[f], s);
      o[j] = f2b(s);
    }
  }
  *(short8*)(Bpk + (size_t)idx * 8) = *(short8*)o;
}

// ---------------------------------------------------------------------------
// K_pg (R9 config, reverted): 98 partition blocks (EPB 8192) + ALL 391 GEMM
// blocks co-resident in one dispatch. Partition: per-wave sub-histograms and
// per-wave scatter counters with intra-bin wave offsets (no cross-wave LDS
// atomic contention); ord[] bin-contiguous so the flush is coalesced bin-runs
// with one cursor atomic per (block,bin). uint4 edge loads.
// ---------------------------------------------------------------------------
__global__ __launch_bounds__(256) void k_pg(
    const float* __restrict__ x, const unsigned short* __restrict__ Bpk,
    unsigned short* __restrict__ pb, unsigned short* __restrict__ sb,
    float* __restrict__ ssrc, float* __restrict__ stgt,
    const int* __restrict__ ei, int* __restrict__ cursor,
    unsigned int* __restrict__ binned, int N, int E, int partB) {
  __shared__ unsigned int ord[EPB];        // 32 KB
  __shared__ int hist_w[4][128];           // per-wave histograms
  __shared__ int woff_[4][128];            // intra-bin wave offsets
  __shared__ int posw_[4][128];            // per-wave running counters
  __shared__ int base_[128], scn[128], mybase[128];
  const int b = blockIdx.x;
  if (b < partB) {
    const int tid = threadIdx.x;
    const int wv = tid >> 6;
    const int e0 = b * EPB;
    const int ne = min(EPB, E - e0);
    const int* srcp = ei;
    const int* tgtp = ei + E;
    for (int i = tid; i < 512; i += 256) {
      ((int*)hist_w)[i] = 0;
      ((int*)posw_)[i] = 0;
    }
    __syncthreads();
    unsigned int pk[32];
#pragma unroll
    for (int j = 0; j < 8; ++j) {
      int e4 = e0 + (j * 256 + tid) * 4;
      if (e4 < E) {  // E%4==0, e4%4==0 -> full uint4 in bounds
        uint4v t4 = *(const uint4v*)(tgtp + e4);
        uint4v s4 = *(const uint4v*)(srcp + e4);
#pragma unroll
        for (int k = 0; k < 4; ++k) {
          pk[j * 4 + k] = (t4[k] << 16) | s4[k];
          atomicAdd(&hist_w[wv][t4[k] >> 9], 1);
        }
      } else {
#pragma unroll
        for (int k = 0; k < 4; ++k) pk[j * 4 + k] = INVALID;
      }
    }
    __syncthreads();
    if (tid < 128) {
      int w0 = hist_w[0][tid], w1 = hist_w[1][tid];
      int w2 = hist_w[2][tid], w3 = hist_w[3][tid];
      woff_[0][tid] = 0;
      woff_[1][tid] = w0;
      woff_[2][tid] = w0 + w1;
      woff_[3][tid] = w0 + w1 + w2;
      scn[tid] = w0 + w1 + w2 + w3;
    }
    __syncthreads();
    int c = (tid < 128) ? scn[tid] : 0;
#pragma unroll
    for (int off = 1; off < 128; off <<= 1) {
      int v = 0;
      if (tid < 128 && tid >= off) v = scn[tid - off];
      __syncthreads();
      if (tid < 128) scn[tid] += v;
      __syncthreads();
    }
    if (tid < 128) {
      base_[tid] = scn[tid] - c;  // exclusive base
      mybase[tid] = (tid < NBIN && c > 0) ? atomicAdd(&cursor[tid], c) : 0;
    }
    __syncthreads();
#pragma unroll
    for (int j = 0; j < 32; ++j) {
      if (pk[j] != INVALID) {
        int bb = pk[j] >> 25;  // = tgt>>9
        int r = atomicAdd(&posw_[wv][bb], 1);
        ord[base_[bb] + woff_[wv][bb] + r] = pk[j];
      }
    }
    __syncthreads();
    for (int i = tid; i < ne; i += 256) {
      unsigned int p = ord[i];
      int bb = p >> 25;
      int gpos = mybase[bb] + (i - base_[bb]);
      if (gpos < (bb + 1) * SEGCAP) binned[gpos] = p;  // coalesced bin-runs
    }
    return;
  }

  // ---- GEMM branch (M=32 structure) ----
  const int wave = threadIdx.x >> 6, lane = threadIdx.x & 63;
  const int m = lane & 15, q = lane >> 4;
  const int r0 = (b - partB) * 128 + wave * 32;

  short8 a[2][4];
#pragma unroll
  for (int g = 0; g < 2; ++g) {
    const int row_a = r0 + g * 16 + m;
#pragma unroll
    for (int ks = 0; ks < 4; ++ks) {
      float4 v0 = make_float4(0.f, 0.f, 0.f, 0.f), v1 = v0;
      if (row_a < N) {
        const float4* xp = (const float4*)(x + (size_t)row_a * 128 + ks * 32 + q * 8);
        v0 = xp[0];
        v1 = xp[1];
      }
      unsigned short o[8];
      o[0] = f2b(v0.x); o[1] = f2b(v0.y); o[2] = f2b(v0.z); o[3] = f2b(v0.w);
      o[4] = f2b(v1.x); o[5] = f2b(v1.y); o[6] = f2b(v1.z); o[7] = f2b(v1.w);
      a[g][ks] = *(short8*)o;
    }
  }

#define LOADB(dst, t)                                                        \
  {                                                                          \
    const unsigned short* bp_ = Bpk + (size_t)((t) * 256 + lane) * 8;        \
    dst[0] = *(const short8*)(bp_ + 0 * 512);                                \
    dst[1] = *(const short8*)(bp_ + 1 * 512);                                \
    dst[2] = *(const short8*)(bp_ + 2 * 512);                                \
    dst[3] = *(const short8*)(bp_ + 3 * 512);                                \
  }

  short8 bb[2][4];
  LOADB(bb[0], 0)
#pragma unroll
  for (int ct = 0; ct < 17; ++ct) {
    if (ct < 16) LOADB(bb[(ct + 1) & 1], ct + 1)
    f32x4 acc0 = {0.f, 0.f, 0.f, 0.f};
    f32x4 acc1 = {0.f, 0.f, 0.f, 0.f};
#pragma unroll
    for (int ks = 0; ks < 4; ++ks) {
      acc0 = __builtin_amdgcn_mfma_f32_16x16x32_bf16(a[0][ks], bb[ct & 1][ks], acc0, 0, 0, 0);
      acc1 = __builtin_amdgcn_mfma_f32_16x16x32_bf16(a[1][ks], bb[ct & 1][ks], acc1, 0, 0, 0);
    }
    if (ct < 16) {
      unsigned short* dst = (ct < 8) ? pb : sb;
      const int cc = (ct & 7) * 16 + m;
#pragma unroll
      for (int r = 0; r < 4; ++r) {
        int row0 = r0 + q * 4 + r;
        if (row0 < N) dst[(size_t)row0 * 128 + cc] = f2b(acc0[r]);
        int row1 = r0 + 16 + q * 4 + r;
        if (row1 < N) dst[(size_t)row1 * 128 + cc] = f2b(acc1[r]);
      }
    } else {  // score tile: cols 0-7 = s_src heads, 8-15 = s_tgt heads
      float* sd = (m < 8) ? ssrc : stgt;
      const int h = m & 7;
#pragma unroll
      for (int r = 0; r < 4; ++r) {
        int row0 = r0 + q * 4 + r;
        if (row0 < N) sd[row0 * 8 + h] = acc0[r];
        int row1 = r0 + 16 + q * 4 + r;
        if (row1 < N) sd[row1 * 8 + h] = acc1[r];
      }
    }
  }
#undef LOADB
}

// ---------------------------------------------------------------------------
// K_csr (R9 config, reverted): 392 quarter-bin blocks. Block (g,q) scans bin
// g's segment (uint4 streaming) and ranks only targets in its 128-node slice
// into a 16 KB LDS bucket, then flushes coalesced.
// ---------------------------------------------------------------------------
__global__ __launch_bounds__(256) void k_csr(const unsigned int* __restrict__ binned,
                                             const int* __restrict__ cursor,
                                             int* __restrict__ counts,
                                             unsigned short* __restrict__ esrc,
                                             int N) {
  __shared__ unsigned short buck[128 * CAP];  // 16 KB
  __shared__ int cnt128[128];
  const int g = blockIdx.x >> 2, qq = blockIdx.x & 3, tid = threadIdx.x;
  const int lo = g * BINSZ + qq * 128;
  for (int i = tid; i < 128; i += 256) cnt128[i] = 0;
  __syncthreads();
  const int cnt = min(cursor[g] - g * SEGCAP, SEGCAP);
  const unsigned int* seg = binned + (size_t)g * SEGCAP;
  const int c4 = cnt >> 2;
  for (int i = tid; i < c4; i += 256) {
    uint4v p4 = *(const uint4v*)(seg + i * 4);
#pragma unroll
    for (int k = 0; k < 4; ++k) {
      unsigned int p = p4[k];
      int tl = (p >> 16) & (BINSZ - 1);
      if ((tl >> 7) == qq) {
        int r = atomicAdd(&cnt128[tl & 127], 1);
        if (r < CAP) buck[((tl & 127) << 6) + r] = (unsigned short)(p & 0xFFFFu);
      }
    }
  }
  for (int i = c4 * 4 + tid; i < cnt; i += 256) {
    unsigned int p = seg[i];
    int tl = (p >> 16) & (BINSZ - 1);
    if ((tl >> 7) == qq) {
      int r = atomicAdd(&cnt128[tl & 127], 1);
      if (r < CAP) buck[((tl & 127) << 6) + r] = (unsigned short)(p & 0xFFFFu);
    }
  }
  __syncthreads();
  uint4* dst = (uint4*)(esrc + ((size_t)lo << 6));
  const uint4* s4 = (const uint4*)buck;
  for (int v = tid; v < (128 * CAP) / 8; v += 256) dst[v] = s4[v];
  for (int i = tid; i < 128; i += 256) {
    int n = lo + i;
    if (n < N) counts[n] = min(cnt128[i], CAP);
  }
}

// ---------------------------------------------------------------------------
// K_agg (R8 VALU-lean version, unchanged): Phase A computes per-slot weights
// for all 8 heads once (lane j owns slot j; 9-padded LDS row); Phase B is
// one broadcast ds_read + one scalar-based pb gather + 2 fma per edge,
// branch-free tail. Fused skip+bias+ELU.
// ---------------------------------------------------------------------------
__global__ __launch_bounds__(256) void k_agg(const unsigned short* __restrict__ pb,
                                             const unsigned short* __restrict__ sb,
                                             const float* __restrict__ ssrc,
                                             const float* __restrict__ stgt,
                                             const float* __restrict__ bias,
                                             const int* __restrict__ counts,
                                             const unsigned short* __restrict__ esrc,
                                             float* __restrict__ out, int N) {
  __shared__ float w_lds[4][64 * 9];
  int wid = (int)((blockIdx.x * (size_t)blockDim.x + threadIdx.x) >> 6);
  int lane = threadIdx.x & 63;
  if (wid >= N) return;
  const int n = wid;
  const int wv = threadIdx.x >> 6;
  const int c = lane * 2;
  const int h = lane >> 3;

  const int cnt = min(counts[n], CAP);
  const int srcv = (int)esrc[(n << 6) + lane];

  {
    const bool val = lane < cnt;
    const int s_safe = val ? srcv : 0;
    const float4* sp = (const float4*)(ssrc + s_safe * 8);
    float4 s01 = sp[0], s23 = sp[1];
    const float4* tp = (const float4*)(stgt + n * 8);
    float4 t01 = tp[0], t23 = tp[1];
    float w[8];
    w[0] = s01.x + t01.x; w[1] = s01.y + t01.y;
    w[2] = s01.z + t01.z; w[3] = s01.w + t01.w;
    w[4] = s23.x + t23.x; w[5] = s23.y + t23.y;
    w[6] = s23.z + t23.z; w[7] = s23.w + t23.w;
#pragma unroll
    for (int k = 0; k < 8; ++k) {
      float e_ = fmaxf(w[k], 0.2f * w[k]);
      w[k] = val ? __expf(e_) : 0.0f;
    }
    float* wr = &w_lds[wv][lane * 9];
#pragma unroll
    for (int k = 0; k < 8; ++k) wr[k] = w[k];
  }

  float ds0 = 0.f, ds1 = 0.f, ds2 = 0.f, ds3 = 0.f;
  float x00 = 0.f, x01 = 0.f, x10 = 0.f, x11 = 0.f;
  float x20 = 0.f, x21 = 0.f, x30 = 0.f, x31 = 0.f;

#define LOADP(p, jj)                                                   \
  {                                                                    \
    int s_ = __builtin_amdgcn_readlane(srcv, min((jj), cm));           \
    pv##p = *(const unsigned int*)(pb + (size_t)s_ * 128 + c);         \
  }
#define CONS(p, dsx, a0x, a1x, jj)                                     \
  {                                                                    \
    float w_ = w_lds[wv][(jj) * 9 + h];                                \
    dsx += w_;                                                         \
    a0x = fmaf(w_, __uint_as_float(pv##p << 16), a0x);                 \
    a1x = fmaf(w_, __uint_as_float(pv##p & 0xffff0000u), a1x);         \
  }

  const int p8 = (cnt + 7) & ~7;
  if (p8 > 0) {
    const int cm = cnt - 1;
    unsigned int pv0, pv1, pv2, pv3, pv4, pv5, pv6, pv7;
    LOADP(0, 0) LOADP(1, 1) LOADP(2, 2) LOADP(3, 3)
    LOADP(4, 4) LOADP(5, 5) LOADP(6, 6) LOADP(7, 7)
    for (int j = 0; j + 8 <= p8; j += 8) {
      CONS(0, ds0, x00, x01, j + 0)
      CONS(1, ds1, x10, x11, j + 1)
      CONS(2, ds2, x20, x21, j + 2)
      CONS(3, ds3, x30, x31, j + 3)
      if (j + 8 < p8) {
        LOADP(0, j + 8) LOADP(1, j + 9) LOADP(2, j + 10) LOADP(3, j + 11)
      }
      CONS(4, ds0, x00, x01, j + 4)
      CONS(5, ds1, x10, x11, j + 5)
      CONS(6, ds2, x20, x21, j + 6)
      CONS(7, ds3, x30, x31, j + 7)
      if (j + 8 < p8) {
        LOADP(4, j + 12) LOADP(5, j + 13) LOADP(6, j + 14) LOADP(7, j + 15)
      }
    }
  }
#undef LOADP
#undef CONS

  const float dsum = (ds0 + ds1) + (ds2 + ds3);
  const float acc0 = (x00 + x10) + (x20 + x30);
  const float acc1 = (x01 + x11) + (x21 + x31);
  const float inv = 1.0f / (dsum + 1e-16f);
  size_t row = (size_t)n * 128;
  unsigned int su = *(const unsigned int*)(sb + row + c);
  float sk0 = __uint_as_float(su << 16);
  float sk1 = __uint_as_float(su & 0xffff0000u);
  float r0 = fmaf(acc0, inv, sk0) + bias[c];
  float r1 = fmaf(acc1, inv, sk1) + bias[c + 1];
  r0 = (r0 > 0.f) ? r0 : (__expf(r0) - 1.0f);  // ELU
  r1 = (r1 > 0.f) ? r1 : (__expf(r1) - 1.0f);
  *(float2*)(out + row + c) = make_float2(r0, r1);
}

// ---------------------------------------------------------------------------
extern "C" void kernel_launch(void* const* d_in, const int* in_sizes, int n_in,
                              void* d_out, int out_size, void* d_ws, size_t ws_size,
                              hipStream_t stream) {
  const float* x = (const float*)d_in[0];
  const int* ei = (const int*)d_in[1];
  const float* Wp = (const float*)d_in[2];
  const float* a_src = (const float*)d_in[3];
  const float* a_tgt = (const float*)d_in[4];
  const float* Ws = (const float*)d_in[5];
  const float* bias = (const float*)d_in[6];
  float* out = (float*)d_out;

  const int N = in_sizes[0] / 128;  // 50000
  const int E = in_sizes[1] / 2;    // 800000

  // workspace layout (~39.1 MB), all 16B-aligned
  unsigned short* Bpk = (unsigned short*)d_ws;            // 34816 bf16
  unsigned short* pb = Bpk + 34816;                       // N*128 bf16
  unsigned short* sb = pb + (size_t)N * 128;              // N*128 bf16
  float* ssrc = (float*)(sb + (size_t)N * 128);           // N*8
  float* stgt = ssrc + (size_t)N * 8;                     // N*8
  int* counts = (int*)(stgt + (size_t)N * 8);             // N
  unsigned short* esrcU = (unsigned short*)(counts + N);  // NBIN*512*64 ushort
  unsigned int* binned = (unsigned int*)(esrcU + (size_t)NBIN * BINSZ * CAP);
  int* cursor = (int*)(binned + (size_t)NBIN * SEGCAP);   // NBIN

  const int partB = (E + EPB - 1) / EPB;  // 98 partition blocks
  const int gemmB = PADN / 128;           // 391 gemm blocks

  k_init<<<18, 256, 0, stream>>>(Wp, Ws, a_src, a_tgt, Bpk, cursor);
  k_pg<<<partB + gemmB, 256, 0, stream>>>(x, Bpk, pb, sb, ssrc, stgt, ei, cursor,
                                          binned, N, E, partB);
  k_csr<<<NBIN * 4, 256, 0, stream>>>(binned, cursor, counts, esrcU, N);
  k_agg<<<(N + 3) / 4, 256, 0, stream>>>(pb, sb, ssrc, stgt, bias, counts, esrcU, out, N);
}